// Round 3
// baseline (565.196 us; speedup 1.0000x reference)
//
#include <hip/hip_runtime.h>

#define S_SPAT 262144   // 64^3
#define NCH 64

// ws float offsets (~21.5KB scratch)
#define WS_XM    0      // [2][64] masked channel sums
#define WS_MH    128    // [2][64]
#define WS_MW    256    // [2][64]
#define WS_MD    384    // [2][64]
#define WS_NPIX  512    // [2]
#define WS_CBIAS 516    // [2]
#define WS_M     518    // [2]
#define WS_COEF  520    // [2]  npix/S
#define WS_WQE   528    // [2][64] effective logit weights (incl /8)
#define WS_QH    656    // [2][64]
#define WS_QW    784    // [2][64]
#define WS_QD    912    // [2][64]
#define WS_QUERY 1040   // [2][64]
#define WS_BLKM  1280   // [2048]
#define WS_BLKS  3328   // [2048]

__device__ inline float waveReduceSum(float v) {
#pragma unroll
    for (int o = 32; o > 0; o >>= 1) v += __shfl_xor(v, o, 64);
    return v;
}
__device__ inline float waveReduceMax(float v) {
#pragma unroll
    for (int o = 32; o > 0; o >>= 1) v = fmaxf(v, __shfl_xor(v, o, 64));
    return v;
}

// ---- mask stats: maskH/maskW/maskD per batch. 128 blocks (b,h), 256 thr ----
__global__ void k_mask_stats(const float* __restrict__ mask, float* __restrict__ ws) {
    int bid = blockIdx.x;
    int b = bid >> 6, h = bid & 63;
    int t = threadIdx.x;
    const float* mp = mask + (size_t)b * S_SPAT + h * 4096;
    float vals[16];
    float sum = 0.f;
#pragma unroll
    for (int j = 0; j < 16; j++) { vals[j] = mp[j * 256 + t]; sum += vals[j]; }
    // element index j*256+t: d = t&63 (fixed per thread), w = 4j + (t>>6)
    __shared__ float ldsD[64];
    __shared__ float ldsW[64];
    __shared__ float wsum[4];
    if (t < 64) { ldsD[t] = 0.f; ldsW[t] = 0.f; }
    __syncthreads();
    int wv = t >> 6, lane = t & 63;
    atomicAdd(&ldsD[lane], sum);
#pragma unroll
    for (int j = 0; j < 16; j++) {
        float w_s = waveReduceSum(vals[j]);
        if (lane == 0) atomicAdd(&ldsW[4 * j + wv], w_s);
    }
    float tot = waveReduceSum(sum);
    if (lane == 0) wsum[wv] = tot;
    __syncthreads();
    if (t == 0) ws[WS_MH + b * 64 + h] = wsum[0] + wsum[1] + wsum[2] + wsum[3];
    if (t < 64) {
        atomicAdd(&ws[WS_MD + b * 64 + t], ldsD[t]);
        atomicAdd(&ws[WS_MW + b * 64 + t], ldsW[t]);
    }
}

// ---- xm[b,c] = sum_s mask*x. 8192 blocks = (b,c,chunk64), 256 thr ----
__global__ void k_xm(const float* __restrict__ x, const float* __restrict__ mask,
                     float* __restrict__ ws) {
    int bid = blockIdx.x;
    int chunk = bid & 63;
    int bc = bid >> 6;            // b*64+c
    int b = bc >> 6;
    int t = threadIdx.x;
    const float4* xp = (const float4*)(x + (size_t)bc * S_SPAT + chunk * 4096);
    const float4* mp = (const float4*)(mask + (size_t)b * S_SPAT + chunk * 4096);
    float acc = 0.f;
#pragma unroll
    for (int j = 0; j < 4; j++) {
        float4 xv = xp[j * 256 + t];
        float4 mv = mp[j * 256 + t];
        acc += xv.x * mv.x + xv.y * mv.y + xv.z * mv.z + xv.w * mv.w;
    }
    __shared__ float wsum[4];
    float tot = waveReduceSum(acc);
    int wv = t >> 6, lane = t & 63;
    if (lane == 0) wsum[wv] = tot;
    __syncthreads();
    if (t == 0) atomicAdd(&ws[WS_XM + bc], wsum[0] + wsum[1] + wsum[2] + wsum[3]);
}

// ---- tiny: query -> effective weights. 1 block, 64 threads ----
__global__ void k_query(const float* __restrict__ Wk, const float* __restrict__ bk,
                        const float* __restrict__ Wq, const float* __restrict__ bq,
                        const float* __restrict__ h_tab, const float* __restrict__ w_tab,
                        const float* __restrict__ d_tab, float* __restrict__ ws) {
    int k = threadIdx.x;  // 0..63
    __shared__ float q_l[2][64];
    for (int b = 0; b < 2; b++) {
        float npix = 0.f;
        for (int h = 0; h < 64; h++) npix += ws[WS_MH + b * 64 + h];
        float acc = bq[k] * npix;
        for (int c = 0; c < 64; c++) acc += Wq[k * 64 + c] * ws[WS_XM + b * 64 + c];
        for (int h = 0; h < 64; h++) acc += h_tab[h * 64 + k] * ws[WS_MH + b * 64 + h];
        for (int w = 0; w < 64; w++) acc += w_tab[w * 64 + k] * ws[WS_MW + b * 64 + w];
        for (int d = 0; d < 64; d++) acc += d_tab[d * 64 + k] * ws[WS_MD + b * 64 + d];
        float q = acc / npix;
        q_l[b][k] = q;
        ws[WS_QUERY + b * 64 + k] = q;
        if (k == 0) ws[WS_NPIX + b] = npix;
    }
    __syncthreads();
    const float inv8 = 0.125f;  // 1/sqrt(64)
    for (int b = 0; b < 2; b++) {
        float we = 0.f, qh = 0.f, qw = 0.f, qd = 0.f, cb = 0.f;
        for (int kk = 0; kk < 64; kk++) {
            float q = q_l[b][kk];
            we += q * Wk[kk * 64 + k];
            qh += q * h_tab[k * 64 + kk];
            qw += q * w_tab[k * 64 + kk];
            qd += q * d_tab[k * 64 + kk];
            cb += q * bk[kk];
        }
        ws[WS_WQE + b * 64 + k] = we * inv8;
        ws[WS_QH + b * 64 + k] = qh * inv8;
        ws[WS_QW + b * 64 + k] = qw * inv8;
        ws[WS_QD + b * 64 + k] = qd * inv8;
        if (k == 0) ws[WS_CBIAS + b] = cb * inv8;
    }
}

// ---- logits + per-block softmax partials. 2048 blocks, 256 thr, 1 vox/thr ----
__global__ void __launch_bounds__(256) k_logits(const float* __restrict__ x,
                                                float* __restrict__ logit_buf,
                                                float* __restrict__ ws) {
    int bid = blockIdx.x;
    int b = bid >> 10;                       // 1024 blocks per batch
    int s = (bid & 1023) * 256 + threadIdx.x;
    const float* xb = x + (size_t)b * NCH * S_SPAT + s;
    const float* wq = &ws[WS_WQE + b * 64];  // wave-uniform -> s_load
    float acc = 0.f;
#pragma unroll
    for (int c = 0; c < 64; c++) acc = fmaf(wq[c], xb[(size_t)c * S_SPAT], acc);
    int h = s >> 12, w = (s >> 6) & 63, d = s & 63;
    float lg = acc + ws[WS_CBIAS + b] + ws[WS_QH + b * 64 + h]
                   + ws[WS_QW + b * 64 + w] + ws[WS_QD + b * 64 + d];
    logit_buf[(size_t)b * S_SPAT + s] = lg;

    __shared__ float red[4];
    int wv = threadIdx.x >> 6, lane = threadIdx.x & 63;
    float wm = waveReduceMax(lg);
    if (lane == 0) red[wv] = wm;
    __syncthreads();
    float mb = fmaxf(fmaxf(red[0], red[1]), fmaxf(red[2], red[3]));
    float e = __expf(lg - mb);
    __syncthreads();
    float es = waveReduceSum(e);
    if (lane == 0) red[wv] = es;
    __syncthreads();
    if (threadIdx.x == 0) {
        ws[WS_BLKM + bid] = mb;
        ws[WS_BLKS + bid] = red[0] + red[1] + red[2] + red[3];
    }
}

// ---- combine 1024 block partials per batch -> M, coef = npix/S ----
__global__ void k_softmax_reduce(float* __restrict__ ws) {
    int b = blockIdx.x;
    int t = threadIdx.x;
    const float* bm = &ws[WS_BLKM + b * 1024];
    const float* bs = &ws[WS_BLKS + b * 1024];
    float m = -1e30f, s = 0.f;
#pragma unroll
    for (int j = 0; j < 4; j++) {
        float mj = bm[t * 4 + j], sj = bs[t * 4 + j];
        float nm = fmaxf(m, mj);
        s = s * __expf(m - nm) + sj * __expf(mj - nm);
        m = nm;
    }
#pragma unroll
    for (int o = 32; o > 0; o >>= 1) {
        float om = __shfl_xor(m, o, 64), os = __shfl_xor(s, o, 64);
        float nm = fmaxf(m, om);
        s = s * __expf(m - nm) + os * __expf(om - nm);
        m = nm;
    }
    __shared__ float rm[4], rs[4];
    int wv = t >> 6, lane = t & 63;
    if (lane == 0) { rm[wv] = m; rs[wv] = s; }
    __syncthreads();
    if (t == 0) {
        float M = rm[0], S = rs[0];
        for (int i = 1; i < 4; i++) {
            float nm = fmaxf(M, rm[i]);
            S = S * __expf(M - nm) + rs[i] * __expf(rm[i] - nm);
            M = nm;
        }
        ws[WS_M + b] = M;
        ws[WS_COEF + b] = ws[WS_NPIX + b] / S;
    }
}

// ---- out[b,co,s] = coef*exp(logit-M) * (Wv.x + bv) ----
// 8192 blocks; block = 64-voxel tile, 4 waves; wave owns 16 co channels.
__global__ void __launch_bounds__(256, 4) k_out(const float* __restrict__ x,
                                                const float* __restrict__ Wv,
                                                const float* __restrict__ bv,
                                                const float* __restrict__ logit_buf,
                                                const float* __restrict__ ws,
                                                float* __restrict__ out) {
    __shared__ float xlds[64][64];
    int v0 = blockIdx.x * 64;         // global voxel base
    int b = v0 >> 18;
    int s0 = v0 & (S_SPAT - 1);
    int t = threadIdx.x;
    // stage x tile [64c][64s]: thread t loads row c=t>>2, 16 floats at (t&3)*16
    {
        int c = t >> 2, o = (t & 3) * 16;
        const float4* src = (const float4*)(x + (size_t)b * NCH * S_SPAT
                                              + (size_t)c * S_SPAT + s0 + o);
        float4* dst = (float4*)(&xlds[c][o]);
#pragma unroll
        for (int j = 0; j < 4; j++) dst[j] = src[j];
    }
    __syncthreads();
    int wid = t >> 6, lane = t & 63;
    float a = ws[WS_COEF + b] * __expf(logit_buf[v0 + lane] - ws[WS_M + b]);
    float xr[64];
#pragma unroll
    for (int c = 0; c < 64; c++) xr[c] = xlds[c][lane];   // bank-conflict-free
    float* ob = out + (size_t)b * NCH * S_SPAT + s0 + lane;
    int co_base = wid * 16;
#pragma unroll
    for (int g = 0; g < 4; g++) {
        int co0 = co_base + g * 4;
        const float* w0 = Wv + co0 * 64;   // wave-uniform rows -> s_load
        float a0 = bv[co0], a1 = bv[co0 + 1], a2 = bv[co0 + 2], a3 = bv[co0 + 3];
#pragma unroll
        for (int c = 0; c < 64; c++) {
            float xv = xr[c];
            a0 = fmaf(w0[c], xv, a0);
            a1 = fmaf(w0[64 + c], xv, a1);
            a2 = fmaf(w0[128 + c], xv, a2);
            a3 = fmaf(w0[192 + c], xv, a3);
        }
        ob[(size_t)(co0 + 0) * S_SPAT] = a * a0;
        ob[(size_t)(co0 + 1) * S_SPAT] = a * a1;
        ob[(size_t)(co0 + 2) * S_SPAT] = a * a2;
        ob[(size_t)(co0 + 3) * S_SPAT] = a * a3;
    }
}

// ---- copy mask into the tail of d_out (also overwrites logit scratch) ----
__global__ void k_copy_mask(const float* __restrict__ mask, float* __restrict__ out_tail) {
    int i = blockIdx.x * 256 + threadIdx.x;
    ((float4*)out_tail)[i] = ((const float4*)mask)[i];
}

extern "C" void kernel_launch(void* const* d_in, const int* in_sizes, int n_in,
                              void* d_out, int out_size, void* d_ws, size_t ws_size,
                              hipStream_t stream) {
    const float* x     = (const float*)d_in[0];
    const float* mask  = (const float*)d_in[1];
    const float* Wk    = (const float*)d_in[2];
    const float* bk    = (const float*)d_in[3];
    const float* Wv    = (const float*)d_in[4];
    const float* bv    = (const float*)d_in[5];
    const float* Wq    = (const float*)d_in[6];
    const float* bq    = (const float*)d_in[7];
    const float* h_tab = (const float*)d_in[8];
    const float* w_tab = (const float*)d_in[9];
    const float* d_tab = (const float*)d_in[10];
    float* ws  = (float*)d_ws;
    float* out = (float*)d_out;
    // logits staged in the mask-slot of d_out (overwritten last by k_copy_mask)
    float* logit_buf = out + (size_t)2 * NCH * S_SPAT;

    hipMemsetAsync(ws, 0, 1024 * sizeof(float), stream);  // zero atomic targets
    k_mask_stats<<<128, 256, 0, stream>>>(mask, ws);
    k_xm<<<8192, 256, 0, stream>>>(x, mask, ws);
    k_query<<<1, 64, 0, stream>>>(Wk, bk, Wq, bq, h_tab, w_tab, d_tab, ws);
    k_logits<<<2048, 256, 0, stream>>>(x, logit_buf, ws);
    k_softmax_reduce<<<2, 256, 0, stream>>>(ws);
    k_out<<<8192, 256, 0, stream>>>(x, Wv, bv, logit_buf, ws, out);
    k_copy_mask<<<512, 256, 0, stream>>>(mask, out + (size_t)2 * NCH * S_SPAT);
}

// Round 4
// 358.286 us; speedup vs baseline: 1.5775x; 1.5775x over previous
//
#include <hip/hip_runtime.h>

#define S_SPAT 262144   // 64^3
#define NCH 64

// ws float offsets (~21.5KB scratch)
#define WS_XM    0      // [2][64] masked channel sums
#define WS_MH    128    // [2][64]
#define WS_MW    256    // [2][64]
#define WS_MD    384    // [2][64]
#define WS_NPIX  512    // [2]
#define WS_CBIAS 516    // [2]
#define WS_M     518    // [2]
#define WS_COEF  520    // [2]  npix/S
#define WS_WQE   528    // [2][64] effective logit weights (incl /8)
#define WS_QH    656    // [2][64]
#define WS_QW    784    // [2][64]
#define WS_QD    912    // [2][64]
#define WS_QUERY 1040   // [2][64]
#define WS_BLKM  1280   // [2048]
#define WS_BLKS  3328   // [2048]

typedef float f32x4 __attribute__((ext_vector_type(4)));
typedef short short8 __attribute__((ext_vector_type(8)));

__device__ inline float waveReduceSum(float v) {
#pragma unroll
    for (int o = 32; o > 0; o >>= 1) v += __shfl_xor(v, o, 64);
    return v;
}
__device__ inline float waveReduceMax(float v) {
#pragma unroll
    for (int o = 32; o > 0; o >>= 1) v = fmaxf(v, __shfl_xor(v, o, 64));
    return v;
}

__device__ inline unsigned short f2bf(float x) {  // RNE
    unsigned int u = __float_as_uint(x);
    return (unsigned short)((u + 0x7FFFu + ((u >> 16) & 1u)) >> 16);
}
__device__ inline unsigned int pk2(float a, float b) {
    return (unsigned int)f2bf(a) | ((unsigned int)f2bf(b) << 16);
}

// ---- mask stats: maskH/maskW/maskD per batch. 128 blocks (b,h), 256 thr ----
__global__ void k_mask_stats(const float* __restrict__ mask, float* __restrict__ ws) {
    int bid = blockIdx.x;
    int b = bid >> 6, h = bid & 63;
    int t = threadIdx.x;
    const float* mp = mask + (size_t)b * S_SPAT + h * 4096;
    float vals[16];
    float sum = 0.f;
#pragma unroll
    for (int j = 0; j < 16; j++) { vals[j] = mp[j * 256 + t]; sum += vals[j]; }
    __shared__ float ldsD[64];
    __shared__ float ldsW[64];
    __shared__ float wsum[4];
    if (t < 64) { ldsD[t] = 0.f; ldsW[t] = 0.f; }
    __syncthreads();
    int wv = t >> 6, lane = t & 63;
    atomicAdd(&ldsD[lane], sum);
#pragma unroll
    for (int j = 0; j < 16; j++) {
        float w_s = waveReduceSum(vals[j]);
        if (lane == 0) atomicAdd(&ldsW[4 * j + wv], w_s);
    }
    float tot = waveReduceSum(sum);
    if (lane == 0) wsum[wv] = tot;
    __syncthreads();
    if (t == 0) ws[WS_MH + b * 64 + h] = wsum[0] + wsum[1] + wsum[2] + wsum[3];
    if (t < 64) {
        atomicAdd(&ws[WS_MD + b * 64 + t], ldsD[t]);
        atomicAdd(&ws[WS_MW + b * 64 + t], ldsW[t]);
    }
}

// ---- xm[b,c] = sum_s mask*x. 8192 blocks = (b,c,chunk64), 256 thr ----
__global__ void k_xm(const float* __restrict__ x, const float* __restrict__ mask,
                     float* __restrict__ ws) {
    int bid = blockIdx.x;
    int chunk = bid & 63;
    int bc = bid >> 6;            // b*64+c
    int b = bc >> 6;
    int t = threadIdx.x;
    const float4* xp = (const float4*)(x + (size_t)bc * S_SPAT + chunk * 4096);
    const float4* mp = (const float4*)(mask + (size_t)b * S_SPAT + chunk * 4096);
    float acc = 0.f;
#pragma unroll
    for (int j = 0; j < 4; j++) {
        float4 xv = xp[j * 256 + t];
        float4 mv = mp[j * 256 + t];
        acc += xv.x * mv.x + xv.y * mv.y + xv.z * mv.z + xv.w * mv.w;
    }
    __shared__ float wsum[4];
    float tot = waveReduceSum(acc);
    int wv = t >> 6, lane = t & 63;
    if (lane == 0) wsum[wv] = tot;
    __syncthreads();
    if (t == 0) atomicAdd(&ws[WS_XM + bc], wsum[0] + wsum[1] + wsum[2] + wsum[3]);
}

// ---- tiny: query -> effective weights. 1 block, 64 threads ----
__global__ void k_query(const float* __restrict__ Wk, const float* __restrict__ bk,
                        const float* __restrict__ Wq, const float* __restrict__ bq,
                        const float* __restrict__ h_tab, const float* __restrict__ w_tab,
                        const float* __restrict__ d_tab, float* __restrict__ ws) {
    int k = threadIdx.x;  // 0..63
    __shared__ float q_l[2][64];
    for (int b = 0; b < 2; b++) {
        float npix = 0.f;
        for (int h = 0; h < 64; h++) npix += ws[WS_MH + b * 64 + h];
        float acc = bq[k] * npix;
        for (int c = 0; c < 64; c++) acc += Wq[k * 64 + c] * ws[WS_XM + b * 64 + c];
        for (int h = 0; h < 64; h++) acc += h_tab[h * 64 + k] * ws[WS_MH + b * 64 + h];
        for (int w = 0; w < 64; w++) acc += w_tab[w * 64 + k] * ws[WS_MW + b * 64 + w];
        for (int d = 0; d < 64; d++) acc += d_tab[d * 64 + k] * ws[WS_MD + b * 64 + d];
        float q = acc / npix;
        q_l[b][k] = q;
        ws[WS_QUERY + b * 64 + k] = q;
        if (k == 0) ws[WS_NPIX + b] = npix;
    }
    __syncthreads();
    const float inv8 = 0.125f;  // 1/sqrt(64)
    for (int b = 0; b < 2; b++) {
        float we = 0.f, qh = 0.f, qw = 0.f, qd = 0.f, cb = 0.f;
        for (int kk = 0; kk < 64; kk++) {
            float q = q_l[b][kk];
            we += q * Wk[kk * 64 + k];
            qh += q * h_tab[k * 64 + kk];
            qw += q * w_tab[k * 64 + kk];
            qd += q * d_tab[k * 64 + kk];
            cb += q * bk[kk];
        }
        ws[WS_WQE + b * 64 + k] = we * inv8;
        ws[WS_QH + b * 64 + k] = qh * inv8;
        ws[WS_QW + b * 64 + k] = qw * inv8;
        ws[WS_QD + b * 64 + k] = qd * inv8;
        if (k == 0) ws[WS_CBIAS + b] = cb * inv8;
    }
}

// ---- logits + per-block softmax partials. 2048 blocks, 256 thr, 1 vox/thr ----
__global__ void __launch_bounds__(256) k_logits(const float* __restrict__ x,
                                                float* __restrict__ logit_buf,
                                                float* __restrict__ ws) {
    int bid = blockIdx.x;
    int b = bid >> 10;                       // 1024 blocks per batch
    int s = (bid & 1023) * 256 + threadIdx.x;
    const float* xb = x + (size_t)b * NCH * S_SPAT + s;
    const float* wq = &ws[WS_WQE + b * 64];  // wave-uniform -> s_load
    float acc = 0.f;
#pragma unroll
    for (int c = 0; c < 64; c++) acc = fmaf(wq[c], xb[(size_t)c * S_SPAT], acc);
    int h = s >> 12, w = (s >> 6) & 63, d = s & 63;
    float lg = acc + ws[WS_CBIAS + b] + ws[WS_QH + b * 64 + h]
                   + ws[WS_QW + b * 64 + w] + ws[WS_QD + b * 64 + d];
    logit_buf[(size_t)b * S_SPAT + s] = lg;

    __shared__ float red[4];
    int wv = threadIdx.x >> 6, lane = threadIdx.x & 63;
    float wm = waveReduceMax(lg);
    if (lane == 0) red[wv] = wm;
    __syncthreads();
    float mb = fmaxf(fmaxf(red[0], red[1]), fmaxf(red[2], red[3]));
    float e = __expf(lg - mb);
    __syncthreads();
    float es = waveReduceSum(e);
    if (lane == 0) red[wv] = es;
    __syncthreads();
    if (threadIdx.x == 0) {
        ws[WS_BLKM + bid] = mb;
        ws[WS_BLKS + bid] = red[0] + red[1] + red[2] + red[3];
    }
}

// ---- combine 1024 block partials per batch -> M, coef = npix/S ----
__global__ void k_softmax_reduce(float* __restrict__ ws) {
    int b = blockIdx.x;
    int t = threadIdx.x;
    const float* bm = &ws[WS_BLKM + b * 1024];
    const float* bs = &ws[WS_BLKS + b * 1024];
    float m = -1e30f, s = 0.f;
#pragma unroll
    for (int j = 0; j < 4; j++) {
        float mj = bm[t * 4 + j], sj = bs[t * 4 + j];
        float nm = fmaxf(m, mj);
        s = s * __expf(m - nm) + sj * __expf(mj - nm);
        m = nm;
    }
#pragma unroll
    for (int o = 32; o > 0; o >>= 1) {
        float om = __shfl_xor(m, o, 64), os = __shfl_xor(s, o, 64);
        float nm = fmaxf(m, om);
        s = s * __expf(m - nm) + os * __expf(om - nm);
        m = nm;
    }
    __shared__ float rm[4], rs[4];
    int wv = t >> 6, lane = t & 63;
    if (lane == 0) { rm[wv] = m; rs[wv] = s; }
    __syncthreads();
    if (t == 0) {
        float M = rm[0], S = rs[0];
        for (int i = 1; i < 4; i++) {
            float nm = fmaxf(M, rm[i]);
            S = S * __expf(M - nm) + rs[i] * __expf(rm[i] - nm);
            M = nm;
        }
        ws[WS_M + b] = M;
        ws[WS_COEF + b] = ws[WS_NPIX + b] / S;
    }
}

// ---- out = a[s]*(Wv.x + bv) via MFMA GEMM. 4096 blocks, 256 thr ----
// Block: 128-voxel tile. LDS: XT bf16 [128s][64c] XOR-swizzled (16KB),
// WvL bf16 [64co][64c] swizzled (8KB), a_lds[128]. Wave w: s-range w*32..+31.
__global__ void __launch_bounds__(256, 4) k_out(const float* __restrict__ x,
                                                const float* __restrict__ Wv,
                                                const float* __restrict__ bv,
                                                const float* __restrict__ logit_buf,
                                                const float* __restrict__ ws,
                                                float* __restrict__ out) {
    __shared__ unsigned short XT[128 * 64];     // [s][c] swizzled
    __shared__ unsigned short WvL[64 * 64];     // [co][c] swizzled
    __shared__ float a_lds[128];
    char* xtb = (char*)XT;
    char* wvb = (char*)WvL;

    int bid = blockIdx.x;
    int b = bid >> 11;                // 2048 blocks per batch
    int s0 = (bid & 2047) * 128;
    int t = threadIdx.x;
    const size_t xbase = (size_t)b * NCH * S_SPAT;

    // ---- stage Wv -> LDS bf16, swizzled: byte = co*128 + ((c*2) ^ ((co&7)<<4))
    {
        int co = t >> 2, pr = t & 3;          // 4 threads per row, 16 c each
        const float* wrow = Wv + co * 64 + pr * 16;
        float wv16[16];
#pragma unroll
        for (int j = 0; j < 4; j++) {
            float4 f = *(const float4*)(wrow + j * 4);
            wv16[j * 4 + 0] = f.x; wv16[j * 4 + 1] = f.y;
            wv16[j * 4 + 2] = f.z; wv16[j * 4 + 3] = f.w;
        }
#pragma unroll
        for (int half = 0; half < 2; half++) {
            int c8 = pr * 16 + half * 8;
            uint4 u;
            u.x = pk2(wv16[half * 8 + 0], wv16[half * 8 + 1]);
            u.y = pk2(wv16[half * 8 + 2], wv16[half * 8 + 3]);
            u.z = pk2(wv16[half * 8 + 4], wv16[half * 8 + 5]);
            u.w = pk2(wv16[half * 8 + 6], wv16[half * 8 + 7]);
            *(uint4*)(wvb + co * 128 + ((c8 * 2) ^ ((co & 7) << 4))) = u;
        }
    }

    // ---- a[s] for this tile
    if (t < 128) {
        float coef = ws[WS_COEF + b], M = ws[WS_M + b];
        a_lds[t] = coef * __expf(logit_buf[(size_t)b * S_SPAT + s0 + t] - M);
    }

    // ---- stage x tile -> XT bf16 transposed+swizzled
    // thread t: s-quad sq=(t&31)*4; c rows cbase..cbase+3 per ch-group.
    {
        int sq = (t & 31) * 4;
        int crh = t >> 5;                  // 0..7
#pragma unroll
        for (int ch = 0; ch < 2; ch++) {
            int cbase = ch * 32 + crh * 4;
            float vv[4][4];
#pragma unroll
            for (int cl = 0; cl < 4; cl++) {
                float4 f = *(const float4*)(x + xbase + (size_t)(cbase + cl) * S_SPAT + s0 + sq);
                vv[cl][0] = f.x; vv[cl][1] = f.y; vv[cl][2] = f.z; vv[cl][3] = f.w;
            }
#pragma unroll
            for (int si = 0; si < 4; si++) {
                int s = sq + si;
                uint2 u;
                u.x = pk2(vv[0][si], vv[1][si]);
                u.y = pk2(vv[2][si], vv[3][si]);
                *(uint2*)(xtb + s * 128 + ((cbase * 2) ^ (((s >> 2) & 7) << 4))) = u;
            }
        }
    }
    __syncthreads();

    // ---- MFMA: wave w computes out[64co][32s] for s-range w*32..+31
    int w = t >> 6, l = t & 63;
    int ln = l & 15, g = l >> 4;

    short8 Bf[2][2];   // [st][kt]
#pragma unroll
    for (int st = 0; st < 2; st++)
#pragma unroll
        for (int kt = 0; kt < 2; kt++) {
            int s = w * 32 + st * 16 + ln;
            int c = kt * 32 + g * 8;
            Bf[st][kt] = *(const short8*)(xtb + s * 128 + ((c * 2) ^ (((s >> 2) & 7) << 4)));
        }
    short8 Af[4][2];   // [cot][kt]
#pragma unroll
    for (int cot = 0; cot < 4; cot++)
#pragma unroll
        for (int kt = 0; kt < 2; kt++) {
            int co = cot * 16 + ln;
            int c = kt * 32 + g * 8;
            Af[cot][kt] = *(const short8*)(wvb + co * 128 + ((c * 2) ^ ((co & 7) << 4)));
        }

    f32x4 acc[4][2];   // [cot][st]
#pragma unroll
    for (int cot = 0; cot < 4; cot++)
#pragma unroll
        for (int st = 0; st < 2; st++) acc[cot][st] = (f32x4){0.f, 0.f, 0.f, 0.f};

#pragma unroll
    for (int kt = 0; kt < 2; kt++)
#pragma unroll
        for (int cot = 0; cot < 4; cot++)
#pragma unroll
            for (int st = 0; st < 2; st++)
                acc[cot][st] = __builtin_amdgcn_mfma_f32_16x16x32_bf16(
                    Af[cot][kt], Bf[st][kt], acc[cot][st], 0, 0, 0);

    // ---- epilogue: out[co][s] = a[s] * (acc + bv[co])
#pragma unroll
    for (int cot = 0; cot < 4; cot++)
#pragma unroll
        for (int st = 0; st < 2; st++) {
            int s_loc = w * 32 + st * 16 + ln;
            float av = a_lds[s_loc];
            size_t sg = (size_t)s0 + s_loc;
#pragma unroll
            for (int r = 0; r < 4; r++) {
                int co = cot * 16 + g * 4 + r;
                float val = av * (acc[cot][st][r] + bv[co]);
                out[((size_t)b * NCH + co) * S_SPAT + sg] = val;
            }
        }
}

// ---- copy mask into the tail of d_out (also overwrites logit scratch) ----
__global__ void k_copy_mask(const float* __restrict__ mask, float* __restrict__ out_tail) {
    int i = blockIdx.x * 256 + threadIdx.x;
    ((float4*)out_tail)[i] = ((const float4*)mask)[i];
}

extern "C" void kernel_launch(void* const* d_in, const int* in_sizes, int n_in,
                              void* d_out, int out_size, void* d_ws, size_t ws_size,
                              hipStream_t stream) {
    const float* x     = (const float*)d_in[0];
    const float* mask  = (const float*)d_in[1];
    const float* Wk    = (const float*)d_in[2];
    const float* bk    = (const float*)d_in[3];
    const float* Wv    = (const float*)d_in[4];
    const float* bv    = (const float*)d_in[5];
    const float* Wq    = (const float*)d_in[6];
    const float* bq    = (const float*)d_in[7];
    const float* h_tab = (const float*)d_in[8];
    const float* w_tab = (const float*)d_in[9];
    const float* d_tab = (const float*)d_in[10];
    float* ws  = (float*)d_ws;
    float* out = (float*)d_out;
    // logits staged in the mask-slot of d_out (overwritten last by k_copy_mask)
    float* logit_buf = out + (size_t)2 * NCH * S_SPAT;

    hipMemsetAsync(ws, 0, 1024 * sizeof(float), stream);  // zero atomic targets
    k_mask_stats<<<128, 256, 0, stream>>>(mask, ws);
    k_xm<<<8192, 256, 0, stream>>>(x, mask, ws);
    k_query<<<1, 64, 0, stream>>>(Wk, bk, Wq, bq, h_tab, w_tab, d_tab, ws);
    k_logits<<<2048, 256, 0, stream>>>(x, logit_buf, ws);
    k_softmax_reduce<<<2, 256, 0, stream>>>(ws);
    k_out<<<4096, 256, 0, stream>>>(x, Wv, bv, logit_buf, ws, out);
    k_copy_mask<<<512, 256, 0, stream>>>(mask, out + (size_t)2 * NCH * S_SPAT);
}